// Round 3
// baseline (1242.302 us; speedup 1.0000x reference)
//
#include <hip/hip_runtime.h>

// CRF loss, T=16384, L=1024. v11: v10's chunk-batched MFMA (depth 64) with the
// exchange transport rebuilt. v10 was MALL-transaction bound: 8192 tagged u64
// agent-atomic loads per block per step (sc1, L2-bypassed, 2x tag overhead,
// spin-amplified) ~= 16MB+/step of MALL traffic -> 14.8us/step.
// v11 protocol (LLVM-blessed release/acquire):
//   publish: plain coalesced stores (4KB payload, no tags) ->
//            __syncthreads -> tid0: atomic RELEASE flag store (waitcnt+wbl2+sc1).
//   gather:  spin RELAXED on 8 per-line party flags -> one ACQUIRE load
//            (buffer_inv) -> plain dwordx4 payload loads (pay[tid*4], fully
//            linear). Plain loads allocate in XCD L2: the 8 parties of a group
//            are co-XCD under round-robin (b%8==g%8, perf heuristic only;
//            correctness is pure release/acquire) -> 7/8 reads become L2 hits.
// Also: single-buffer qs (32KB), 2 barriers/step, reg-side per-chunk max
// (bitwise-identical across parties), conflict-free XOR swizzle for both
// staging writes and MFMA b128 reads. Math identical to v10 (absmax 0).

#define TT    16384
#define LLAB  1024
#define NEGV  -10000.0
#define BQ    64            // steps per chunk
#define NCH   256           // chunks per direction (TT/BQ)
#define KCH   16            // chunks per group (= MFMA N)
#define NPTY  8             // parties per group
#define AGT   __HIP_MEMORY_SCOPE_AGENT

typedef unsigned long long u64;
typedef unsigned int u32;
typedef unsigned short u16;
typedef _Float16 f16;
typedef _Float16 h2 __attribute__((ext_vector_type(2)));
typedef _Float16 f16x8 __attribute__((ext_vector_type(8)));
typedef float f32x4 __attribute__((ext_vector_type(4)));

__device__ __forceinline__ u32 pack2(float a, float b) {
  h2 h = {(f16)a, (f16)b};
  return __builtin_bit_cast(u32, h);
}
__device__ __forceinline__ float f16lo(u32 b) {
  return (float)__builtin_bit_cast(f16, (u16)(b & 0xFFFFu));
}
__device__ __forceinline__ float f16hi(u32 b) {
  return (float)__builtin_bit_cast(f16, (u16)(b >> 16));
}
// XOR swizzle on u32-index within a chunk's 512-u32 block (keeps 16B align).
__device__ __forceinline__ int swz(int c, int w) { return w ^ ((c & 7) << 2); }

__device__ __forceinline__ float max8(uint4 v) {
  float m = fmaxf(fmaxf(f16lo(v.x), f16hi(v.x)), fmaxf(f16lo(v.y), f16hi(v.y)));
  m = fmaxf(m, fmaxf(f16lo(v.z), f16hi(v.z)));
  m = fmaxf(m, fmaxf(f16lo(v.w), f16hi(v.w)));
  return m;
}

// ---------------- gold path score (unchanged, proven) ----------------
__global__ __launch_bounds__(256) void crf_gold(const float* __restrict__ pred,
                                                const int* __restrict__ ref,
                                                const float* __restrict__ trans,
                                                float* __restrict__ gold) {
  int t = blockIdx.x * 256 + threadIdx.x;
  int r = ref[t];
  int prev = (t == 0) ? (LLAB - 2) : ref[t - 1];    // START = L-2
  float v = trans[(size_t)r * LLAB + prev] + pred[(size_t)t * LLAB + r];
  if (t == TT - 1) v += trans[(size_t)(LLAB - 1) * LLAB + r];  // STOP row
#pragma unroll
  for (int off = 32; off >= 1; off >>= 1) v += __shfl_xor(v, off);
  __shared__ float acc[4];
  if ((threadIdx.x & 63) == 0) acc[threadIdx.x >> 6] = v;
  __syncthreads();
  if (threadIdx.x == 0) atomicAdd(gold, acc[0] + acc[1] + acc[2] + acc[3]);
}

// ---------------- transpose trans (for bwd row-major frag loads) -------------
__global__ __launch_bounds__(256) void transpose_k(const float* __restrict__ in,
                                                   float* __restrict__ out) {
  __shared__ float t[32][33];
  int bx = blockIdx.x & 31, by = blockIdx.x >> 5;
  int r0 = by * 32, c0 = bx * 32;
  int lr = threadIdx.x >> 3;        // 0..31
  int lc = threadIdx.x & 7;         // 8 x float4
  float4 v = *(const float4*)&in[(size_t)(r0 + lr) * LLAB + c0 + 4 * lc];
  t[lr][4 * lc] = v.x; t[lr][4 * lc + 1] = v.y;
  t[lr][4 * lc + 2] = v.z; t[lr][4 * lc + 3] = v.w;
  __syncthreads();
  float4 o = {t[4 * lc][lr], t[4 * lc + 1][lr], t[4 * lc + 2][lr], t[4 * lc + 3][lr]};
  *(float4*)&out[(size_t)(c0 + lr) * LLAB + r0 + 4 * lc] = o;
}

// ---------------- chunk-batched fwd/bwd propagation ----------------
__global__ __launch_bounds__(256, 1) void crf_chunks(
    const float* __restrict__ pred, const float* __restrict__ trans,
    const float* __restrict__ transT, u32* __restrict__ pay,
    u32* __restrict__ fl, float* __restrict__ ybuf,
    float* __restrict__ zbuf, double* __restrict__ tlog) {
  const int tid = threadIdx.x;
  const int wv = tid >> 6, l = tid & 63;
  const int lm = l & 15, lg = l >> 4;        // chunk-lane / k-group
  const int gc = tid >> 4, tp = tid & 15;    // gather: chunk / slot
  const int b = blockIdx.x;
  const int g = b & 31;                      // group (co-XCD parties: b%8==g%8)
  const int party = b >> 5;                  // 0..7
  const bool isFwd = (g < 16);
  const int cbase = (g & 15) * KCH;
  const int myChunk = cbase + lm;
  const int tb = myChunk * BQ;
  const int wb = 128 * party + 32 * wv;      // wave's first output row

  // ---- E fragments: A[m=lm][k=32*kt+8*lg+j] = exp(M[row][k]); M=trans (fwd)
  // or transT (bwd: A' = E^T rows = trans columns = transT rows).
  const float* M = isFwd ? trans : transT;
  f16x8 afrag0[32], afrag1[32];
  {
    const float4* rp0 = (const float4*)&M[(size_t)(wb + lm) * LLAB];
    const float4* rp1 = (const float4*)&M[(size_t)(wb + 16 + lm) * LLAB];
#pragma unroll
    for (int kt = 0; kt < 32; ++kt) {
      float4 a = rp0[8 * kt + 2 * lg], c = rp0[8 * kt + 2 * lg + 1];
      f16x8 f;
      f[0] = (f16)__expf(a.x); f[1] = (f16)__expf(a.y);
      f[2] = (f16)__expf(a.z); f[3] = (f16)__expf(a.w);
      f[4] = (f16)__expf(c.x); f[5] = (f16)__expf(c.y);
      f[6] = (f16)__expf(c.z); f[7] = (f16)__expf(c.w);
      afrag0[kt] = f;
      a = rp1[8 * kt + 2 * lg]; c = rp1[8 * kt + 2 * lg + 1];
      f[0] = (f16)__expf(a.x); f[1] = (f16)__expf(a.y);
      f[2] = (f16)__expf(a.z); f[3] = (f16)__expf(a.w);
      f[4] = (f16)__expf(c.x); f[5] = (f16)__expf(c.y);
      f[6] = (f16)__expf(c.z); f[7] = (f16)__expf(c.w);
      afrag1[kt] = f;
    }
  }

  __shared__ __attribute__((aligned(16))) u32 qs[16 * 512];   // 32 KB
  __shared__ float smax[16];

  u32* gpay = pay + (size_t)g * 16384;   // [2 parity][8 party][1024 u32]
  u32* gfl  = fl + (size_t)g * 512;      // [2 parity][8 party x 32-stride]

  // ---- init state: thread owns chunk gc, labels 64*tp..64*tp+63
  {
    float mm;
    if (isFwd) {
      uint4 ones = {0x3C003C00u, 0x3C003C00u, 0x3C003C00u, 0x3C003C00u};
#pragma unroll
      for (int u2 = 0; u2 < 8; ++u2)
        *(uint4*)&qs[gc * 512 + swz(gc, 32 * tp + 4 * u2)] = ones;
      mm = 1.0f;
    } else {
      int trow = (cbase + gc) * BQ + BQ - 1;
      const float2* pp = (const float2*)&pred[(size_t)trow * LLAB + 64 * tp];
      mm = 0.f;
#pragma unroll
      for (int u2 = 0; u2 < 8; ++u2) {
        float2 e0 = pp[4 * u2], e1 = pp[4 * u2 + 1];
        float2 e2 = pp[4 * u2 + 2], e3 = pp[4 * u2 + 3];
        float a0 = __expf(e0.x), a1 = __expf(e0.y);
        float a2 = __expf(e1.x), a3 = __expf(e1.y);
        float a4 = __expf(e2.x), a5 = __expf(e2.y);
        float a6 = __expf(e3.x), a7 = __expf(e3.y);
        uint4 w4 = {pack2(a0, a1), pack2(a2, a3), pack2(a4, a5), pack2(a6, a7)};
        *(uint4*)&qs[gc * 512 + swz(gc, 32 * tp + 4 * u2)] = w4;
        mm = fmaxf(mm, fmaxf(fmaxf(a0, a1), fmaxf(a2, a3)));
        mm = fmaxf(mm, fmaxf(fmaxf(a4, a5), fmaxf(a6, a7)));
      }
#pragma unroll
      for (int off = 1; off <= 8; off <<= 1) mm = fmaxf(mm, __shfl_xor(mm, off));
    }
    if (tp == 0) smax[gc] = mm;
  }
  __syncthreads();

  // emission prefetch for step 0 (fwd: t=tb; bwd: t=tb+62, input-side)
  float4 fe0, fe1;
  {
    int tn = isFwd ? tb : (tb + BQ - 2);
    fe0 = *(const float4*)&pred[(size_t)tn * LLAB + wb + 4 * lg];
    fe1 = *(const float4*)&pred[(size_t)tn * LLAB + wb + 16 + 4 * lg];
  }

  const float C0 = 13359.727f;   // e^9.5 growth prior; residual tracked via u
  double up = 1.0;

  for (int s = 0; s < BQ; ++s) {
    const bool lastS = (s == BQ - 1);
    const int ps = s & 1;
    const u32 want = (u32)(s + 1);
    const float u = smax[lm];
    if (tid < 16) up *= (double)smax[tid];
    const float inv = 1.0f / (C0 * u);

    // MFMA: 2 row-tiles x 32 k-tiles; B-frag from swizzled LDS
    f32x4 acc0 = {0.f, 0.f, 0.f, 0.f}, acc1 = {0.f, 0.f, 0.f, 0.f};
#pragma unroll
    for (int kt = 0; kt < 32; ++kt) {
      f16x8 bf = __builtin_bit_cast(f16x8,
          *(const uint4*)&qs[lm * 512 + swz(lm, 16 * kt + 4 * lg)]);
      acc0 = __builtin_amdgcn_mfma_f32_16x16x32_f16(afrag0[kt], bf, acc0, 0, 0, 0);
      acc1 = __builtin_amdgcn_mfma_f32_16x16x32_f16(afrag1[kt], bf, acc1, 0, 0, 0);
    }

    // prefetch next step's emission rows (in flight across publish+spin)
    float4 nf0 = fe0, nf1 = fe1;
    if (!lastS) {
      int sn = s + 1;
      int tn = isFwd ? (tb + sn) : (tb + BQ - 2 - sn);
      if (tn < tb) tn = tb;      // bwd sn=63 value unused
      nf0 = *(const float4*)&pred[(size_t)tn * LLAB + wb + 4 * lg];
      nf1 = *(const float4*)&pred[(size_t)tn * LLAB + wb + 16 + 4 * lg];
    }

    // fold emission (fwd: output-side; bwd: input-side for next matvec) + norm
    const bool fold = isFwd || !lastS;
    float o0[4], o1[4];
    if (fold) {
      o0[0] = acc0[0] * __expf(fe0.x) * inv; o0[1] = acc0[1] * __expf(fe0.y) * inv;
      o0[2] = acc0[2] * __expf(fe0.z) * inv; o0[3] = acc0[3] * __expf(fe0.w) * inv;
      o1[0] = acc1[0] * __expf(fe1.x) * inv; o1[1] = acc1[1] * __expf(fe1.y) * inv;
      o1[2] = acc1[2] * __expf(fe1.z) * inv; o1[3] = acc1[3] * __expf(fe1.w) * inv;
    } else {
#pragma unroll
      for (int r = 0; r < 4; ++r) { o0[r] = acc0[r] * inv; o1[r] = acc1[r] * inv; }
    }

    if (lastS) {  // write final chunk vector (f32) to global
      float* dst = isFwd ? ybuf : zbuf;
      size_t base = (size_t)myChunk * LLAB + wb + 4 * lg;
#pragma unroll
      for (int r = 0; r < 4; ++r) {
        dst[base + r] = o0[r];
        dst[base + 16 + r] = o1[r];
      }
      break;
    }

    // publish payload: plain coalesced stores (labels 32wv+4lg.., chunk lm)
    {
      u32* op = gpay + (size_t)ps * 8192 + party * 1024 + lm * 64 + 16 * wv + 2 * lg;
      uint2 q0 = {pack2(o0[0], o0[1]), pack2(o0[2], o0[3])};
      uint2 q1 = {pack2(o1[0], o1[1]), pack2(o1[2], o1[3])};
      *(uint2*)op = q0;
      *(uint2*)(op + 8) = q1;
    }
    __syncthreads();   // all waves' stores drained (vmcnt0); qs reads done
    if (tid == 0)      // RELEASE: waitcnt + buffer_wbl2 + sc1 flag store
      __hip_atomic_store(gfl + ps * 256 + party * 32, want, __ATOMIC_RELEASE, AGT);

    // spin on 8 per-line party flags (relaxed), then one ACQUIRE (buffer_inv)
    {
      const u32* fp = gfl + ps * 256 + (l & 7) * 32;
      bool done = false;
      do {
        if (!done) done = (__hip_atomic_load(fp, __ATOMIC_RELAXED, AGT) >= want);
      } while (!__all(done));
      (void)__hip_atomic_load(fp, __ATOMIC_ACQUIRE, AGT);
    }

    // gather 8 parties x 16B (plain, fully linear: pay[tid*4]); stage + max
    {
      const u32* pb = gpay + (size_t)ps * 8192 + tid * 4;
      uint4 gv[8];
#pragma unroll
      for (int p2 = 0; p2 < 8; ++p2) gv[p2] = *(const uint4*)(pb + p2 * 1024);
      float mm = 0.f;
#pragma unroll
      for (int p2 = 0; p2 < 8; ++p2) {
        *(uint4*)&qs[gc * 512 + swz(gc, 64 * p2 + 4 * tp)] = gv[p2];
        mm = fmaxf(mm, max8(gv[p2]));
      }
#pragma unroll
      for (int off = 1; off <= 8; off <<= 1) mm = fmaxf(mm, __shfl_xor(mm, off));
      if (tp == 0) smax[gc] = mm;
    }
    __syncthreads();   // staging + smax complete
    fe0 = nf0; fe1 = nf1;
  }

  // record bwd tau (log u products; stitch adds BQ*log(C0)); fwd tau cancels
  if (!isFwd && party == 0 && tid < 16) tlog[cbase + tid] = log(up);
}

// ---------------- rank-1 stitch: one block per seam, f64 ----------------
__global__ __launch_bounds__(256) void crf_stitch(
    const float* __restrict__ ybuf, const float* __restrict__ zbuf,
    const double* __restrict__ tlog, double* __restrict__ dacc) {
  const int cc = blockIdx.x, tid = threadIdx.x;
  double na = 0.0, sa = 0.0;
  for (int j = tid; j < LLAB; j += 256) {
    double yv = (double)ybuf[(size_t)cc * LLAB + j];
    na += yv;
    double zz = (cc + 1 < NCH) ? (double)zbuf[(size_t)(cc + 1) * LLAB + j] : 1.0;
    sa += zz * yv;
  }
#pragma unroll
  for (int off = 32; off >= 1; off >>= 1) {
    na += __shfl_xor(na, off);
    sa += __shfl_xor(sa, off);
  }
  __shared__ double red[2][4];
  if ((tid & 63) == 0) { red[0][tid >> 6] = na; red[1][tid >> 6] = sa; }
  __syncthreads();
  if (tid == 0) {
    double n = red[0][0] + red[0][1] + red[0][2] + red[0][3];
    double sm = red[1][0] + red[1][1] + red[1][2] + red[1][3];
    const double LC0 = log((double)13359.727f);
    atomicAdd(dacc, log(sm) - log(n) + tlog[cc] + (double)BQ * LC0);
  }
}

__global__ void crf_final(const double* __restrict__ dacc,
                          const float* __restrict__ zbuf,
                          const float* __restrict__ gold,
                          float* __restrict__ out) {
  double s = dacc[0] + log((double)zbuf[LLAB - 2]) + NEGV - (double)gold[0];
  out[0] = (float)s;
}

extern "C" void kernel_launch(void* const* d_in, const int* in_sizes, int n_in,
                              void* d_out, int out_size, void* d_ws, size_t ws_size,
                              hipStream_t stream) {
  const float* pred  = (const float*)d_in[0];   // (16384, 1024) f32
  const int*   ref   = (const int*)d_in[1];     // (16384,) i32
  const float* trans = (const float*)d_in[2];   // (1024, 1024) f32
  float* out = (float*)d_out;

  char* ws = (char*)d_ws;
  double* dacc = (double*)(ws + 0);                        // 8 B
  float* gold  = (float*)(ws + 8);                         // 4 B
  float* transT = (float*)(ws + 1024);                     // 4 MB
  size_t off = 1024 + (size_t)LLAB * LLAB * 4;
  u32* pay = (u32*)(ws + off);                             // 32*2*8*1024*4 = 2 MB
  off += (size_t)32 * 2 * NPTY * 1024 * 4;
  u32* fl = (u32*)(ws + off);                              // 32*512*4 = 64 KB
  const size_t flbytes = (size_t)32 * 512 * 4;
  off += flbytes;
  float* ybuf = (float*)(ws + off); off += (size_t)NCH * LLAB * 4;   // 1 MB
  float* zbuf = (float*)(ws + off); off += (size_t)NCH * LLAB * 4;   // 1 MB
  double* tlog = (double*)(ws + off);                      // 2 KB

  hipMemsetAsync(ws, 0, 256, stream);            // dacc + gold
  hipMemsetAsync(fl, 0, flbytes, stream);        // reset flags every launch
  transpose_k<<<1024, 256, 0, stream>>>(trans, transT);
  crf_gold<<<64, 256, 0, stream>>>(pred, ref, trans, gold);
  crf_chunks<<<256, 256, 0, stream>>>(pred, trans, transT, pay, fl, ybuf, zbuf, tlog);
  crf_stitch<<<NCH, 256, 0, stream>>>(ybuf, zbuf, tlog, dacc);
  crf_final<<<1, 1, 0, stream>>>(dacc, zbuf, gold, out);
}

// Round 4
// 373.162 us; speedup vs baseline: 3.3291x; 3.3291x over previous
//
#include <hip/hip_runtime.h>

// CRF loss, T=16384, L=1024. v12: depth 32 + maintenance-free transport.
// v11 regressed (1158us, VALUBusy 4%): per-step RELEASE(buffer_wbl2) +
// per-wave ACQUIRE(buffer_inv = whole-L2 invalidate) = 65K cache-maintenance
// ops; latency-bound worsened. v12:
//  - transport: payload = relaxed sc1 ATOMIC stores (write-through to MALL, no
//    dirty L2 lines) -> __syncthreads (compiler emits s_waitcnt vmcnt(0): all
//    payload acked at coherence point) -> one relaxed per-party FLAG store.
//    Readers spin on 8 flag lines only, then pull untagged payload EXACTLY
//    ONCE with 32 pipelined relaxed atomic u64 loads (1 MALL RT; no tags, no
//    re-sweep, no wbl2/inv ever). 2-parity slots, flag monotone (s+1).
//  - depth: BQ=32 (Perron rank-1 to 1e-44), NCH=512, KCH=32 chunks/group
//    (two MFMA B-tiles: chunks lm, lm+16), 32 groups x 8 parties = 256 blocks
//    (all co-resident on 256 CUs). 128 MFMA/step/wave.
// Math/normalization/stitch identical to proven v10 (absmax 0 there).

#define TT    16384
#define LLAB  1024
#define NEGV  -10000.0
#define BQ    32            // steps per chunk
#define NCH   512           // chunks per direction (TT/BQ)
#define KCH   32            // chunks per group (2 MFMA N-tiles)
#define NPTY  8             // parties per group
#define AGT   __HIP_MEMORY_SCOPE_AGENT

typedef unsigned long long u64;
typedef unsigned int u32;
typedef unsigned short u16;
typedef _Float16 f16;
typedef _Float16 h2 __attribute__((ext_vector_type(2)));
typedef _Float16 f16x8 __attribute__((ext_vector_type(8)));
typedef float f32x4 __attribute__((ext_vector_type(4)));

__device__ __forceinline__ void pub64(u64* p, u64 v) {
  __hip_atomic_store(p, v, __ATOMIC_RELAXED, AGT);
}
__device__ __forceinline__ u64 ald64(const u64* p) {
  return __hip_atomic_load(p, __ATOMIC_RELAXED, AGT);
}
__device__ __forceinline__ u32 pack2(float a, float b) {
  h2 h = {(f16)a, (f16)b};
  return __builtin_bit_cast(u32, h);
}
__device__ __forceinline__ float f16lo(u32 b) {
  return (float)__builtin_bit_cast(f16, (u16)(b & 0xFFFFu));
}
__device__ __forceinline__ float f16hi(u32 b) {
  return (float)__builtin_bit_cast(f16, (u16)(b >> 16));
}
// XOR swizzle on u32-word index within a chunk's 512-word block (bits 2..4).
__device__ __forceinline__ int swz(int c, int w) { return w ^ ((c & 7) << 2); }

__device__ __forceinline__ float max4(u32 a, u32 b) {
  return fmaxf(fmaxf(f16lo(a), f16hi(a)), fmaxf(f16lo(b), f16hi(b)));
}

// ---------------- gold path score (unchanged, proven) ----------------
__global__ __launch_bounds__(256) void crf_gold(const float* __restrict__ pred,
                                                const int* __restrict__ ref,
                                                const float* __restrict__ trans,
                                                float* __restrict__ gold) {
  int t = blockIdx.x * 256 + threadIdx.x;
  int r = ref[t];
  int prev = (t == 0) ? (LLAB - 2) : ref[t - 1];    // START = L-2
  float v = trans[(size_t)r * LLAB + prev] + pred[(size_t)t * LLAB + r];
  if (t == TT - 1) v += trans[(size_t)(LLAB - 1) * LLAB + r];  // STOP row
#pragma unroll
  for (int off = 32; off >= 1; off >>= 1) v += __shfl_xor(v, off);
  __shared__ float acc[4];
  if ((threadIdx.x & 63) == 0) acc[threadIdx.x >> 6] = v;
  __syncthreads();
  if (threadIdx.x == 0) atomicAdd(gold, acc[0] + acc[1] + acc[2] + acc[3]);
}

// ---------------- transpose trans (for bwd row-major frag loads) -------------
__global__ __launch_bounds__(256) void transpose_k(const float* __restrict__ in,
                                                   float* __restrict__ out) {
  __shared__ float t[32][33];
  int bx = blockIdx.x & 31, by = blockIdx.x >> 5;
  int r0 = by * 32, c0 = bx * 32;
  int lr = threadIdx.x >> 3;        // 0..31
  int lc = threadIdx.x & 7;         // 8 x float4
  float4 v = *(const float4*)&in[(size_t)(r0 + lr) * LLAB + c0 + 4 * lc];
  t[lr][4 * lc] = v.x; t[lr][4 * lc + 1] = v.y;
  t[lr][4 * lc + 2] = v.z; t[lr][4 * lc + 3] = v.w;
  __syncthreads();
  float4 o = {t[4 * lc][lr], t[4 * lc + 1][lr], t[4 * lc + 2][lr], t[4 * lc + 3][lr]};
  *(float4*)&out[(size_t)(c0 + lr) * LLAB + r0 + 4 * lc] = o;
}

// ---------------- chunk-batched fwd/bwd propagation ----------------
__global__ __launch_bounds__(256, 1) void crf_chunks(
    const float* __restrict__ pred, const float* __restrict__ trans,
    const float* __restrict__ transT, u64* __restrict__ pay,
    u32* __restrict__ fl, float* __restrict__ ybuf,
    float* __restrict__ zbuf, double* __restrict__ tlog) {
  const int tid = threadIdx.x;
  const int wv = tid >> 6, l = tid & 63;
  const int lm = l & 15, lg = l >> 4;        // MFMA lane coords
  const int gc = tid >> 3, tp = tid & 7;     // gather: chunk / slot
  const int b = blockIdx.x;
  const int g = b & 31;                      // group 0..31
  const int party = b >> 5;                  // 0..7
  const bool isFwd = (g < 16);
  const int cbase = (g & 15) * KCH;
  const int c1 = cbase + lm, c2 = cbase + lm + 16;
  const int tb1 = c1 * BQ, tb2 = c2 * BQ;
  const int wb = 128 * party + 32 * wv;      // wave's first output row

  // ---- E fragments: A[m=lm][k=32*kt+8*lg+j] = exp(M[row][k]); M=trans (fwd)
  // or transT (bwd: E^T rows = trans cols = transT rows).
  const float* M = isFwd ? trans : transT;
  f16x8 afrag0[32], afrag1[32];
  {
    const float4* rp0 = (const float4*)&M[(size_t)(wb + lm) * LLAB];
    const float4* rp1 = (const float4*)&M[(size_t)(wb + 16 + lm) * LLAB];
#pragma unroll
    for (int kt = 0; kt < 32; ++kt) {
      float4 a = rp0[8 * kt + 2 * lg], c = rp0[8 * kt + 2 * lg + 1];
      f16x8 f;
      f[0] = (f16)__expf(a.x); f[1] = (f16)__expf(a.y);
      f[2] = (f16)__expf(a.z); f[3] = (f16)__expf(a.w);
      f[4] = (f16)__expf(c.x); f[5] = (f16)__expf(c.y);
      f[6] = (f16)__expf(c.z); f[7] = (f16)__expf(c.w);
      afrag0[kt] = f;
      a = rp1[8 * kt + 2 * lg]; c = rp1[8 * kt + 2 * lg + 1];
      f[0] = (f16)__expf(a.x); f[1] = (f16)__expf(a.y);
      f[2] = (f16)__expf(a.z); f[3] = (f16)__expf(a.w);
      f[4] = (f16)__expf(c.x); f[5] = (f16)__expf(c.y);
      f[6] = (f16)__expf(c.z); f[7] = (f16)__expf(c.w);
      afrag1[kt] = f;
    }
  }

  __shared__ __attribute__((aligned(16))) u32 qs[KCH * 512];   // 64 KB
  __shared__ float smax[KCH];

  u64* gp64 = pay + (size_t)g * 16384;   // [2 parity][8 party][1024 u64]
  u32* gfl  = fl + (size_t)g * 512;      // [2 parity][8 party x 32-stride]

  // ---- init state: thread owns chunk gc, words 64*tp..64*tp+63 (labels x128)
  {
    float mm;
    if (isFwd) {
      uint4 ones = {0x3C003C00u, 0x3C003C00u, 0x3C003C00u, 0x3C003C00u};
#pragma unroll
      for (int i = 0; i < 16; ++i)
        *(uint4*)&qs[gc * 512 + swz(gc, 64 * tp + 4 * i)] = ones;
      mm = 1.0f;
    } else {
      int trow = (cbase + gc) * BQ + BQ - 1;
      const float4* pp = (const float4*)&pred[(size_t)trow * LLAB + 128 * tp];
      mm = 0.f;
#pragma unroll
      for (int i = 0; i < 16; ++i) {
        float4 e0 = pp[2 * i], e1 = pp[2 * i + 1];
        float a0 = __expf(e0.x), a1 = __expf(e0.y);
        float a2 = __expf(e0.z), a3 = __expf(e0.w);
        float a4 = __expf(e1.x), a5 = __expf(e1.y);
        float a6 = __expf(e1.z), a7 = __expf(e1.w);
        uint4 w4 = {pack2(a0, a1), pack2(a2, a3), pack2(a4, a5), pack2(a6, a7)};
        *(uint4*)&qs[gc * 512 + swz(gc, 64 * tp + 4 * i)] = w4;
        mm = fmaxf(mm, fmaxf(fmaxf(a0, a1), fmaxf(a2, a3)));
        mm = fmaxf(mm, fmaxf(fmaxf(a4, a5), fmaxf(a6, a7)));
      }
#pragma unroll
      for (int off = 1; off <= 4; off <<= 1) mm = fmaxf(mm, __shfl_xor(mm, off));
    }
    if (tp == 0) smax[gc] = mm;
  }
  __syncthreads();

  // emission prefetch for step 0 (fwd: t=tb; bwd: t=tb+BQ-2, input-side)
  float4 fe1a, fe1b, fe2a, fe2b;
  {
    int t1 = isFwd ? tb1 : (tb1 + BQ - 2);
    int t2 = isFwd ? tb2 : (tb2 + BQ - 2);
    fe1a = *(const float4*)&pred[(size_t)t1 * LLAB + wb + 4 * lg];
    fe1b = *(const float4*)&pred[(size_t)t1 * LLAB + wb + 16 + 4 * lg];
    fe2a = *(const float4*)&pred[(size_t)t2 * LLAB + wb + 4 * lg];
    fe2b = *(const float4*)&pred[(size_t)t2 * LLAB + wb + 16 + 4 * lg];
  }

  const float C0 = 13359.727f;   // e^9.5 growth prior; residual tracked via u
  double up = 1.0;

  for (int s = 0; s < BQ; ++s) {
    const bool lastS = (s == BQ - 1);
    const int ps = s & 1;
    const u32 want = (u32)(s + 1);
    if (tid < KCH) up *= (double)smax[tid];
    const float i1 = 1.0f / (C0 * smax[lm]);
    const float i2 = 1.0f / (C0 * smax[lm + 16]);

    // MFMA: 2 row-tiles x 2 chunk-tiles x 32 k-tiles; B from swizzled LDS
    f32x4 a00 = {0.f, 0.f, 0.f, 0.f}, a01 = {0.f, 0.f, 0.f, 0.f};
    f32x4 a10 = {0.f, 0.f, 0.f, 0.f}, a11 = {0.f, 0.f, 0.f, 0.f};
#pragma unroll
    for (int kt = 0; kt < 32; ++kt) {
      f16x8 b1 = __builtin_bit_cast(f16x8,
          *(const uint4*)&qs[lm * 512 + swz(lm, 16 * kt + 4 * lg)]);
      f16x8 b2 = __builtin_bit_cast(f16x8,
          *(const uint4*)&qs[(lm + 16) * 512 + swz(lm + 16, 16 * kt + 4 * lg)]);
      a00 = __builtin_amdgcn_mfma_f32_16x16x32_f16(afrag0[kt], b1, a00, 0, 0, 0);
      a01 = __builtin_amdgcn_mfma_f32_16x16x32_f16(afrag1[kt], b1, a01, 0, 0, 0);
      a10 = __builtin_amdgcn_mfma_f32_16x16x32_f16(afrag0[kt], b2, a10, 0, 0, 0);
      a11 = __builtin_amdgcn_mfma_f32_16x16x32_f16(afrag1[kt], b2, a11, 0, 0, 0);
    }

    // prefetch next step's emission rows (in flight across publish+spin)
    float4 n1a = fe1a, n1b = fe1b, n2a = fe2a, n2b = fe2b;
    if (!lastS) {
      int sn = s + 1;
      int t1 = isFwd ? (tb1 + sn) : (tb1 + BQ - 2 - sn);
      int t2 = isFwd ? (tb2 + sn) : (tb2 + BQ - 2 - sn);
      if (t1 < tb1) t1 = tb1;     // bwd sn=BQ-1 value unused
      if (t2 < tb2) t2 = tb2;
      n1a = *(const float4*)&pred[(size_t)t1 * LLAB + wb + 4 * lg];
      n1b = *(const float4*)&pred[(size_t)t1 * LLAB + wb + 16 + 4 * lg];
      n2a = *(const float4*)&pred[(size_t)t2 * LLAB + wb + 4 * lg];
      n2b = *(const float4*)&pred[(size_t)t2 * LLAB + wb + 16 + 4 * lg];
    }

    // fold emission (fwd: output-side; bwd: input-side for next matvec) + norm
    const bool fold = isFwd || !lastS;
    float o00[4], o01[4], o10[4], o11[4];
    if (fold) {
      o00[0] = a00[0] * __expf(fe1a.x) * i1; o00[1] = a00[1] * __expf(fe1a.y) * i1;
      o00[2] = a00[2] * __expf(fe1a.z) * i1; o00[3] = a00[3] * __expf(fe1a.w) * i1;
      o01[0] = a01[0] * __expf(fe1b.x) * i1; o01[1] = a01[1] * __expf(fe1b.y) * i1;
      o01[2] = a01[2] * __expf(fe1b.z) * i1; o01[3] = a01[3] * __expf(fe1b.w) * i1;
      o10[0] = a10[0] * __expf(fe2a.x) * i2; o10[1] = a10[1] * __expf(fe2a.y) * i2;
      o10[2] = a10[2] * __expf(fe2a.z) * i2; o10[3] = a10[3] * __expf(fe2a.w) * i2;
      o11[0] = a11[0] * __expf(fe2b.x) * i2; o11[1] = a11[1] * __expf(fe2b.y) * i2;
      o11[2] = a11[2] * __expf(fe2b.z) * i2; o11[3] = a11[3] * __expf(fe2b.w) * i2;
    } else {
#pragma unroll
      for (int r = 0; r < 4; ++r) {
        o00[r] = a00[r] * i1; o01[r] = a01[r] * i1;
        o10[r] = a10[r] * i2; o11[r] = a11[r] * i2;
      }
    }

    if (lastS) {  // write final chunk vectors (f32) to global
      float* dst = isFwd ? ybuf : zbuf;
      size_t b1 = (size_t)c1 * LLAB + wb + 4 * lg;
      size_t b2 = (size_t)c2 * LLAB + wb + 4 * lg;
#pragma unroll
      for (int r = 0; r < 4; ++r) {
        dst[b1 + r] = o00[r]; dst[b1 + 16 + r] = o01[r];
        dst[b2 + r] = o10[r]; dst[b2 + 16 + r] = o11[r];
      }
      break;
    }

    // publish: 4 relaxed sc1 atomic u64 stores (untagged payload -> MALL)
    {
      u64* op = gp64 + (size_t)ps * 8192 + party * 1024;
      int i64 = lm * 32 + 8 * wv + lg;
      pub64(op + i64,       ((u64)pack2(o00[2], o00[3]) << 32) | pack2(o00[0], o00[1]));
      pub64(op + i64 + 4,   ((u64)pack2(o01[2], o01[3]) << 32) | pack2(o01[0], o01[1]));
      pub64(op + i64 + 512, ((u64)pack2(o10[2], o10[3]) << 32) | pack2(o10[0], o10[1]));
      pub64(op + i64 + 516, ((u64)pack2(o11[2], o11[3]) << 32) | pack2(o11[0], o11[1]));
    }
    __syncthreads();   // s_waitcnt vmcnt(0): payload acked at MALL; qs reads done
    if (tid == 0)      // flag (relaxed; ordering established by the drain above)
      __hip_atomic_store(gfl + ps * 256 + party * 32, want, __ATOMIC_RELAXED, AGT);

    // spin on 8 per-line party flags only (tiny traffic)
    {
      const u32* fp = gfl + ps * 256 + (l & 7) * 32;
      bool done = false;
      do {
        if (!done) done = (__hip_atomic_load(fp, __ATOMIC_RELAXED, AGT) >= want);
      } while (!__all(done));
    }

    // pull payload EXACTLY ONCE: 8 parties x 4 u64 (all 32 loads in flight)
    {
      u64 gv[8][4];
#pragma unroll
      for (int p2 = 0; p2 < 8; ++p2) {
        const u64* pb = gp64 + (size_t)ps * 8192 + p2 * 1024 + tid * 4;
#pragma unroll
        for (int j = 0; j < 4; ++j) gv[p2][j] = ald64(pb + j);
      }
      float mm = 0.f;
#pragma unroll
      for (int p2 = 0; p2 < 8; ++p2) {
#pragma unroll
        for (int j = 0; j < 4; ++j) {
          u32 lo = (u32)gv[p2][j], hi = (u32)(gv[p2][j] >> 32);
          int W = p2 * 64 + 8 * tp + 2 * j;
          uint2 st = {lo, hi};
          *(uint2*)&qs[gc * 512 + swz(gc, W)] = st;
          mm = fmaxf(mm, max4(lo, hi));
        }
      }
#pragma unroll
      for (int off = 1; off <= 4; off <<= 1) mm = fmaxf(mm, __shfl_xor(mm, off));
      if (tp == 0) smax[gc] = mm;
    }
    __syncthreads();   // staging + smax complete
    fe1a = n1a; fe1b = n1b; fe2a = n2a; fe2b = n2b;
  }

  // record bwd tau (log u products; stitch adds BQ*log(C0)); fwd tau cancels
  if (!isFwd && party == 0 && tid < KCH) tlog[cbase + tid] = log(up);
}

// ---------------- rank-1 stitch: one block per seam, f64 ----------------
__global__ __launch_bounds__(256) void crf_stitch(
    const float* __restrict__ ybuf, const float* __restrict__ zbuf,
    const double* __restrict__ tlog, double* __restrict__ dacc) {
  const int cc = blockIdx.x, tid = threadIdx.x;
  double na = 0.0, sa = 0.0;
  for (int j = tid; j < LLAB; j += 256) {
    double yv = (double)ybuf[(size_t)cc * LLAB + j];
    na += yv;
    double zz = (cc + 1 < NCH) ? (double)zbuf[(size_t)(cc + 1) * LLAB + j] : 1.0;
    sa += zz * yv;
  }
#pragma unroll
  for (int off = 32; off >= 1; off >>= 1) {
    na += __shfl_xor(na, off);
    sa += __shfl_xor(sa, off);
  }
  __shared__ double red[2][4];
  if ((tid & 63) == 0) { red[0][tid >> 6] = na; red[1][tid >> 6] = sa; }
  __syncthreads();
  if (tid == 0) {
    double n = red[0][0] + red[0][1] + red[0][2] + red[0][3];
    double sm = red[1][0] + red[1][1] + red[1][2] + red[1][3];
    const double LC0 = log((double)13359.727f);
    atomicAdd(dacc, log(sm) - log(n) + tlog[cc] + (double)BQ * LC0);
  }
}

__global__ void crf_final(const double* __restrict__ dacc,
                          const float* __restrict__ zbuf,
                          const float* __restrict__ gold,
                          float* __restrict__ out) {
  double s = dacc[0] + log((double)zbuf[LLAB - 2]) + NEGV - (double)gold[0];
  out[0] = (float)s;
}

extern "C" void kernel_launch(void* const* d_in, const int* in_sizes, int n_in,
                              void* d_out, int out_size, void* d_ws, size_t ws_size,
                              hipStream_t stream) {
  const float* pred  = (const float*)d_in[0];   // (16384, 1024) f32
  const int*   ref   = (const int*)d_in[1];     // (16384,) i32
  const float* trans = (const float*)d_in[2];   // (1024, 1024) f32
  float* out = (float*)d_out;

  char* ws = (char*)d_ws;
  double* dacc = (double*)(ws + 0);                        // 8 B
  float* gold  = (float*)(ws + 8);                         // 4 B
  float* transT = (float*)(ws + 1024);                     // 4 MB
  size_t off = 1024 + (size_t)LLAB * LLAB * 4;
  u64* pay = (u64*)(ws + off);                             // 32*2*8*1024*8 = 4 MB
  off += (size_t)32 * 2 * NPTY * 1024 * 8;
  u32* fl = (u32*)(ws + off);                              // 32*512*4 = 64 KB
  const size_t flbytes = (size_t)32 * 512 * 4;
  off += flbytes;
  float* ybuf = (float*)(ws + off); off += (size_t)NCH * LLAB * 4;   // 2 MB
  float* zbuf = (float*)(ws + off); off += (size_t)NCH * LLAB * 4;   // 2 MB
  double* tlog = (double*)(ws + off);                      // 4 KB

  hipMemsetAsync(ws, 0, 256, stream);            // dacc + gold
  hipMemsetAsync(fl, 0, flbytes, stream);        // reset flags every launch
  transpose_k<<<1024, 256, 0, stream>>>(trans, transT);
  crf_gold<<<64, 256, 0, stream>>>(pred, ref, trans, gold);
  crf_chunks<<<256, 256, 0, stream>>>(pred, trans, transT, pay, fl, ybuf, zbuf, tlog);
  crf_stitch<<<NCH, 256, 0, stream>>>(ybuf, zbuf, tlog, dacc);
  crf_final<<<1, 1, 0, stream>>>(dacc, zbuf, gold, out);
}